// Round 2
// baseline (117.593 us; speedup 1.0000x reference)
//
#include <hip/hip_runtime.h>

namespace {
constexpr int XP = 264;        // f16 pixel pitch (33 chunks of 16B, ch 256..263 pad)
constexpr int XR = 18 * XP;    // halo row pitch (18 px: 16 + 2 w-halo)
constexpr int EWP = 148;       // ew pixel pitch (floats)

typedef _Float16 h2 __attribute__((ext_vector_type(2)));
typedef _Float16 h8 __attribute__((ext_vector_type(8)));
typedef float f32x4 __attribute__((ext_vector_type(4)));

__device__ __forceinline__ h2 pkrtz(float a, float b) {
  return __builtin_bit_cast(h2, __builtin_amdgcn_cvt_pkrtz(a, b));
}

#if __has_builtin(__builtin_amdgcn_fdot2)
#define HAS_FDOT2 1
#else
#define HAS_FDOT2 0
#endif

// ---- prep: W12 = W1*W2 packed in f16 B-frag order, b12 = b1*W2 + b2 ----
__global__ __launch_bounds__(256) void prep_w12(
    const float* __restrict__ W1, const float* __restrict__ b1,
    const float* __restrict__ W2, const float* __restrict__ b2,
    _Float16* __restrict__ pack, float* __restrict__ b12)
{
  const int t = threadIdx.x;
  const int T = blockIdx.x;
  if (T < 9) {
    __shared__ float sw2[64 * 16];
    for (int i = t; i < 1024; i += 256) {
      int d = i >> 4, n = i & 15;
      sw2[i] = W2[d * 144 + T * 16 + n];
    }
    __syncthreads();
    const int c = t;
    float acc[16];
#pragma unroll
    for (int n = 0; n < 16; ++n) acc[n] = 0.f;
    for (int d = 0; d < 64; d += 4) {
      float4 w1 = *(const float4*)(W1 + c * 64 + d);
#pragma unroll
      for (int dd = 0; dd < 4; ++dd) {
        float a = (dd == 0) ? w1.x : (dd == 1) ? w1.y : (dd == 2) ? w1.z : w1.w;
        const float* r = &sw2[(d + dd) * 16];
#pragma unroll
        for (int n = 0; n < 16; ++n) acc[n] += a * r[n];
      }
    }
    int s = c >> 5, q = (c >> 3) & 3, j = c & 7;
#pragma unroll
    for (int n = 0; n < 16; ++n)
      pack[(((T * 8 + s) * 64 + q * 16 + n) << 3) + j] = (_Float16)acc[n];
  } else if (t < 144) {
    float bb = b2[t];
    for (int d = 0; d < 64; ++d) bb += b1[d] * W2[d * 144 + t];
    b12[t] = bb;
  }
}

// ---- fused: 2 rows x 16 px per block, 512 thr, 2 blocks/CU (16 waves/CU) ----
// Halo amp 3.375x -> 2.25x; each wave reuses its B tile for both output rows.
__global__ __launch_bounds__(512, 4) void invo_fused(
    const float* __restrict__ x,
    const _Float16* __restrict__ pack,
    const float* __restrict__ b12g,
    float* __restrict__ out)
{
  __shared__ __align__(16) _Float16 xg[4 * XR];   // 38,016 B f16 halo [row][px][ch]
  __shared__ float ew[32 * EWP];                  // 18,944 B fp32 e-weights [p][144]
                                                  // 56,960 B -> 2 blocks/CU

  const int t = threadIdx.x;
  const int blk = blockIdx.x;               // XCD swizzle: b = blk & 7
  const int b = blk & 7;
  const int r_ = blk >> 3;                  // 0..127
  const int strip = r_ & 3;
  const int hp = r_ >> 2;                   // 0..31
  const int h = hp << 1;                    // output rows h, h+1
  const int w0 = strip << 4;
  const int wave = t >> 6, lane = t & 63;

  // ---- B prefetch: wave w owns T = w (overlaps staging) ----
  h8 Bpre[8];
  {
    const h8* bp = (const h8*)pack + (wave * 8) * 64 + lane;
#pragma unroll
    for (int s = 0; s < 8; ++s) Bpre[s] = bp[s * 64];
  }

  // ---- stage 4 rows x 18 px x 256 ch fp32 -> f16; 2304 chunks, loads first ----
  {
    float4 va[5][2];
    int dst[5];
    bool ok[5];
#pragma unroll
    for (int i = 0; i < 5; ++i) {
      int idx = i * 512 + t;
      ok[i] = idx < 2304;
      int cc = idx & 31;                    // 16B chunk within pixel (0..31)
      int pj = idx >> 5;                    // 0..71
      int r = (pj >= 54) ? 3 : (pj >= 36) ? 2 : (pj >= 18) ? 1 : 0;
      int j = pj - r * 18;
      int hh = h + r - 1, ww = w0 + j - 1;
      dst[i] = r * XR + j * XP + cc * 8;
      va[i][0] = make_float4(0.f, 0.f, 0.f, 0.f);
      va[i][1] = make_float4(0.f, 0.f, 0.f, 0.f);
      if (ok[i] && ((unsigned)hh < 64u) && ((unsigned)ww < 64u)) {
        const float* src = x + ((((b << 6) + hh) << 6) + ww) * 256 + cc * 8;
        va[i][0] = *(const float4*)(src);
        va[i][1] = *(const float4*)(src + 4);
      }
    }
#pragma unroll
    for (int i = 0; i < 5; ++i) {
      if (ok[i]) {
        uint4 o;
        o.x = __builtin_bit_cast(unsigned, pkrtz(va[i][0].x, va[i][0].y));
        o.y = __builtin_bit_cast(unsigned, pkrtz(va[i][0].z, va[i][0].w));
        o.z = __builtin_bit_cast(unsigned, pkrtz(va[i][1].x, va[i][1].y));
        o.w = __builtin_bit_cast(unsigned, pkrtz(va[i][1].z, va[i][1].w));
        *(uint4*)(&xg[dst[i]]) = o;
      }
    }
  }
  __syncthreads();

  // ---- GEMM via MFMA: e[p][e] = b12[e] + sum_c x[p][c] * W12[c][e] ----
  // wave w computes T = w for BOTH rows (B reuse); waves 0/1 mop up T = 8.
  {
    const int q = lane >> 4, m = lane & 15;
    h8 A[8];
    const _Float16* a0 = &xg[XR + (m + 1) * XP + q * 8];
    // half 0 (output row h)
#pragma unroll
    for (int s = 0; s < 8; ++s) A[s] = *(const h8*)(a0 + s * 32);
    {
      f32x4 acc = {0.f, 0.f, 0.f, 0.f};
#pragma unroll
      for (int s = 0; s < 8; ++s)
        acc = __builtin_amdgcn_mfma_f32_16x16x32_f16(A[s], Bpre[s], acc, 0, 0, 0);
      float bb = b12g[wave * 16 + m];
#pragma unroll
      for (int r = 0; r < 4; ++r)
        ew[(q * 4 + r) * EWP + wave * 16 + m] = acc[r] + bb;
    }
    // half 1 (output row h+1), same B
#pragma unroll
    for (int s = 0; s < 8; ++s) A[s] = *(const h8*)(a0 + XR + s * 32);
    {
      f32x4 acc = {0.f, 0.f, 0.f, 0.f};
#pragma unroll
      for (int s = 0; s < 8; ++s)
        acc = __builtin_amdgcn_mfma_f32_16x16x32_f16(A[s], Bpre[s], acc, 0, 0, 0);
      float bb = b12g[wave * 16 + m];
#pragma unroll
      for (int r = 0; r < 4; ++r)
        ew[(16 + q * 4 + r) * EWP + wave * 16 + m] = acc[r] + bb;
    }
    // T = 8 leftover: wave 0 -> row h, wave 1 -> row h+1 (B reuses Bpre regs)
    if (wave < 2) {
      const _Float16* ar = a0 + (wave ? XR : 0);
#pragma unroll
      for (int s = 0; s < 8; ++s) A[s] = *(const h8*)(ar + s * 32);
      const h8* bp = (const h8*)pack + 64 * 64 + lane;   // (8*8)*64
#pragma unroll
      for (int s = 0; s < 8; ++s) Bpre[s] = bp[s * 64];
      f32x4 acc = {0.f, 0.f, 0.f, 0.f};
#pragma unroll
      for (int s = 0; s < 8; ++s)
        acc = __builtin_amdgcn_mfma_f32_16x16x32_f16(A[s], Bpre[s], acc, 0, 0, 0);
      float bb = b12g[128 + m];
#pragma unroll
      for (int r = 0; r < 4; ++r)
        ew[(wave * 16 + q * 4 + r) * EWP + 128 + m] = acc[r] + bb;
    }
  }
  __syncthreads();

  // ---- involution: thread=(p 0..31, g); 18x ds_read_b128 + dot2 ----
  {
    const int p = t >> 4, g = t & 15;
    const int hi = p >> 4, pl = p & 15;
    float ewr[9];
#pragma unroll
    for (int k = 0; k < 9; ++k) ewr[k] = ew[p * EWP + g * 9 + k];
    h2 wp[8];
#pragma unroll
    for (int m = 0; m < 8; ++m)
      wp[m] = pkrtz(ewr[m], ewr[m + 1]);
    const float w8 = ewr[8], wb0 = ewr[0];
    const int g144 = g * 144;
    const int pbase = hi * XR + pl * XP;
    float res[16];
#pragma unroll
    for (int gc = 0; gc < 16; ++gc) res[gc] = 0.f;
#pragma unroll
    for (int j = 0; j < 18; ++j) {
      int f = g144 + j * 8;
      int tap = f >> 8;                     // constant within the 8-chunk
      int ch = f & 255;
      int di = (tap * 86) >> 8;             // tap/3
      int off = XP * (tap + 15 * di) + ch;  // di*XR + (tap-3di)*XP + ch
      uint4 dv = *(const uint4*)(&xg[pbase + off]);
      h2 v[4];
      v[0] = __builtin_bit_cast(h2, dv.x);
      v[1] = __builtin_bit_cast(h2, dv.y);
      v[2] = __builtin_bit_cast(h2, dv.z);
      v[3] = __builtin_bit_cast(h2, dv.w);
#pragma unroll
      for (int i = 0; i < 4; ++i) {
        const int u = j * 8 + 2 * i;        // compile-time
        const int m = u % 9;
        if (m == 8) {                       // pair crosses gc boundary
          res[u / 9]     += (float)v[i][0] * w8;
          res[u / 9 + 1] += (float)v[i][1] * wb0;
        } else {
#if HAS_FDOT2
          res[u / 9] = __builtin_amdgcn_fdot2(v[i], wp[m], res[u / 9], false);
#else
          res[u / 9] += (float)v[i][0] * ewr[m] + (float)v[i][1] * ewr[m + 1];
#endif
        }
      }
    }
    float* orow = out + (size_t)((((b << 6) + h + hi) << 6) + w0 + pl) * 256 + (g << 4);
    f32x4 o0 = {res[0],  res[1],  res[2],  res[3]};
    f32x4 o1 = {res[4],  res[5],  res[6],  res[7]};
    f32x4 o2 = {res[8],  res[9],  res[10], res[11]};
    f32x4 o3 = {res[12], res[13], res[14], res[15]};
    __builtin_nontemporal_store(o0, (f32x4*)(orow + 0));
    __builtin_nontemporal_store(o1, (f32x4*)(orow + 4));
    __builtin_nontemporal_store(o2, (f32x4*)(orow + 8));
    __builtin_nontemporal_store(o3, (f32x4*)(orow + 12));
  }
}
} // namespace

extern "C" void kernel_launch(void* const* d_in, const int* in_sizes, int n_in,
                              void* d_out, int out_size, void* d_ws, size_t ws_size,
                              hipStream_t stream) {
  const float* x  = (const float*)d_in[0];
  const float* W1 = (const float*)d_in[1];
  const float* b1 = (const float*)d_in[2];
  const float* W2 = (const float*)d_in[3];
  const float* b2 = (const float*)d_in[4];
  float* out = (float*)d_out;
  _Float16* pack = (_Float16*)d_ws;                        // 73,728 B
  float* b12 = (float*)((char*)d_ws + 73728);              // 576 B
  prep_w12<<<10, 256, 0, stream>>>(W1, b1, W2, b2, pack, b12);
  invo_fused<<<1024, 512, 0, stream>>>(x, pack, b12, out);
}

// Round 3
// 107.789 us; speedup vs baseline: 1.0910x; 1.0910x over previous
//
#include <hip/hip_runtime.h>

namespace {
constexpr int XP = 264;        // f16 pixel pitch (33 chunks of 16B, ch 256..263 pad)
constexpr int XR = 18 * XP;    // halo row pitch (18 px: 16 + 2 w-halo)
constexpr int EWP = 148;       // ew pixel pitch (floats)

typedef _Float16 h2 __attribute__((ext_vector_type(2)));
typedef _Float16 h8 __attribute__((ext_vector_type(8)));
typedef float f32x4 __attribute__((ext_vector_type(4)));

__device__ __forceinline__ h2 pkrtz(float a, float b) {
  return __builtin_bit_cast(h2, __builtin_amdgcn_cvt_pkrtz(a, b));
}

#if __has_builtin(__builtin_amdgcn_fdot2)
#define HAS_FDOT2 1
#else
#define HAS_FDOT2 0
#endif

// ---- prep: W12 = W1*W2 packed in f16 B-frag order, b12 = b1*W2 + b2 ----
__global__ __launch_bounds__(256) void prep_w12(
    const float* __restrict__ W1, const float* __restrict__ b1,
    const float* __restrict__ W2, const float* __restrict__ b2,
    _Float16* __restrict__ pack, float* __restrict__ b12)
{
  const int t = threadIdx.x;
  const int T = blockIdx.x;
  if (T < 9) {
    __shared__ float sw2[64 * 16];
    for (int i = t; i < 1024; i += 256) {
      int d = i >> 4, n = i & 15;
      sw2[i] = W2[d * 144 + T * 16 + n];
    }
    __syncthreads();
    const int c = t;
    float acc[16];
#pragma unroll
    for (int n = 0; n < 16; ++n) acc[n] = 0.f;
    for (int d = 0; d < 64; d += 4) {
      float4 w1 = *(const float4*)(W1 + c * 64 + d);
#pragma unroll
      for (int dd = 0; dd < 4; ++dd) {
        float a = (dd == 0) ? w1.x : (dd == 1) ? w1.y : (dd == 2) ? w1.z : w1.w;
        const float* r = &sw2[(d + dd) * 16];
#pragma unroll
        for (int n = 0; n < 16; ++n) acc[n] += a * r[n];
      }
    }
    int s = c >> 5, q = (c >> 3) & 3, j = c & 7;
#pragma unroll
    for (int n = 0; n < 16; ++n)
      pack[(((T * 8 + s) * 64 + q * 16 + n) << 3) + j] = (_Float16)acc[n];
  } else if (t < 144) {
    float bb = b2[t];
    for (int d = 0; d < 64; ++d) bb += b1[d] * W2[d * 144 + t];
    b12[t] = bb;
  }
}

// ---- fused: 2 rows x 16 px per block, 512 thr, 2 blocks/CU (16 waves/CU) ----
// Halo amp 3.375x -> 2.25x; each wave reuses its B tile for both output rows.
// R2 lesson: nontemporal output stores regressed +7us -> plain stores here.
__global__ __launch_bounds__(512, 4) void invo_fused(
    const float* __restrict__ x,
    const _Float16* __restrict__ pack,
    const float* __restrict__ b12g,
    float* __restrict__ out)
{
  __shared__ __align__(16) _Float16 xg[4 * XR];   // 38,016 B f16 halo [row][px][ch]
  __shared__ float ew[32 * EWP];                  // 18,944 B fp32 e-weights [p][144]
                                                  // 56,960 B -> 2 blocks/CU

  const int t = threadIdx.x;
  const int blk = blockIdx.x;               // XCD swizzle: b = blk & 7
  const int b = blk & 7;
  const int r_ = blk >> 3;                  // 0..127
  const int strip = r_ & 3;
  const int hp = r_ >> 2;                   // 0..31
  const int h = hp << 1;                    // output rows h, h+1
  const int w0 = strip << 4;
  const int wave = t >> 6, lane = t & 63;

  // ---- B prefetch: wave w owns T = w (overlaps staging) ----
  h8 Bpre[8];
  {
    const h8* bp = (const h8*)pack + (wave * 8) * 64 + lane;
#pragma unroll
    for (int s = 0; s < 8; ++s) Bpre[s] = bp[s * 64];
  }

  // ---- stage 4 rows x 18 px x 256 ch fp32 -> f16; 2304 chunks, loads first ----
  {
    float4 va[5][2];
    int dst[5];
    bool ok[5];
#pragma unroll
    for (int i = 0; i < 5; ++i) {
      int idx = i * 512 + t;
      ok[i] = idx < 2304;
      int cc = idx & 31;                    // 16B chunk within pixel (0..31)
      int pj = idx >> 5;                    // 0..71
      int r = (pj >= 54) ? 3 : (pj >= 36) ? 2 : (pj >= 18) ? 1 : 0;
      int j = pj - r * 18;
      int hh = h + r - 1, ww = w0 + j - 1;
      dst[i] = r * XR + j * XP + cc * 8;
      va[i][0] = make_float4(0.f, 0.f, 0.f, 0.f);
      va[i][1] = make_float4(0.f, 0.f, 0.f, 0.f);
      if (ok[i] && ((unsigned)hh < 64u) && ((unsigned)ww < 64u)) {
        const float* src = x + ((((b << 6) + hh) << 6) + ww) * 256 + cc * 8;
        va[i][0] = *(const float4*)(src);
        va[i][1] = *(const float4*)(src + 4);
      }
    }
#pragma unroll
    for (int i = 0; i < 5; ++i) {
      if (ok[i]) {
        uint4 o;
        o.x = __builtin_bit_cast(unsigned, pkrtz(va[i][0].x, va[i][0].y));
        o.y = __builtin_bit_cast(unsigned, pkrtz(va[i][0].z, va[i][0].w));
        o.z = __builtin_bit_cast(unsigned, pkrtz(va[i][1].x, va[i][1].y));
        o.w = __builtin_bit_cast(unsigned, pkrtz(va[i][1].z, va[i][1].w));
        *(uint4*)(&xg[dst[i]]) = o;
      }
    }
  }
  __syncthreads();

  // ---- GEMM via MFMA: e[p][e] = b12[e] + sum_c x[p][c] * W12[c][e] ----
  // wave w computes T = w for BOTH rows (B reuse); waves 0/1 mop up T = 8.
  {
    const int q = lane >> 4, m = lane & 15;
    h8 A[8];
    const _Float16* a0 = &xg[XR + (m + 1) * XP + q * 8];
    // half 0 (output row h)
#pragma unroll
    for (int s = 0; s < 8; ++s) A[s] = *(const h8*)(a0 + s * 32);
    {
      f32x4 acc = {0.f, 0.f, 0.f, 0.f};
#pragma unroll
      for (int s = 0; s < 8; ++s)
        acc = __builtin_amdgcn_mfma_f32_16x16x32_f16(A[s], Bpre[s], acc, 0, 0, 0);
      float bb = b12g[wave * 16 + m];
#pragma unroll
      for (int r = 0; r < 4; ++r)
        ew[(q * 4 + r) * EWP + wave * 16 + m] = acc[r] + bb;
    }
    // half 1 (output row h+1), same B
#pragma unroll
    for (int s = 0; s < 8; ++s) A[s] = *(const h8*)(a0 + XR + s * 32);
    {
      f32x4 acc = {0.f, 0.f, 0.f, 0.f};
#pragma unroll
      for (int s = 0; s < 8; ++s)
        acc = __builtin_amdgcn_mfma_f32_16x16x32_f16(A[s], Bpre[s], acc, 0, 0, 0);
      float bb = b12g[wave * 16 + m];
#pragma unroll
      for (int r = 0; r < 4; ++r)
        ew[(16 + q * 4 + r) * EWP + wave * 16 + m] = acc[r] + bb;
    }
    // T = 8 leftover: wave 0 -> row h, wave 1 -> row h+1
    if (wave < 2) {
      const _Float16* ar = a0 + (wave ? XR : 0);
#pragma unroll
      for (int s = 0; s < 8; ++s) A[s] = *(const h8*)(ar + s * 32);
      const h8* bp = (const h8*)pack + 64 * 64 + lane;   // (8*8)*64
#pragma unroll
      for (int s = 0; s < 8; ++s) Bpre[s] = bp[s * 64];
      f32x4 acc = {0.f, 0.f, 0.f, 0.f};
#pragma unroll
      for (int s = 0; s < 8; ++s)
        acc = __builtin_amdgcn_mfma_f32_16x16x32_f16(A[s], Bpre[s], acc, 0, 0, 0);
      float bb = b12g[128 + m];
#pragma unroll
      for (int r = 0; r < 4; ++r)
        ew[(wave * 16 + q * 4 + r) * EWP + 128 + m] = acc[r] + bb;
    }
  }
  __syncthreads();

  // ---- involution: thread=(p 0..31, g); 18x ds_read_b128 + dot2 ----
  {
    const int p = t >> 4, g = t & 15;
    const int hi = p >> 4, pl = p & 15;
    float ewr[9];
#pragma unroll
    for (int k = 0; k < 9; ++k) ewr[k] = ew[p * EWP + g * 9 + k];
    h2 wp[8];
#pragma unroll
    for (int m = 0; m < 8; ++m)
      wp[m] = pkrtz(ewr[m], ewr[m + 1]);
    const float w8 = ewr[8], wb0 = ewr[0];
    const int g144 = g * 144;
    const int pbase = hi * XR + pl * XP;
    float res[16];
#pragma unroll
    for (int gc = 0; gc < 16; ++gc) res[gc] = 0.f;
#pragma unroll
    for (int j = 0; j < 18; ++j) {
      int f = g144 + j * 8;
      int tap = f >> 8;                     // constant within the 8-chunk
      int ch = f & 255;
      int di = (tap * 86) >> 8;             // tap/3
      int off = XP * (tap + 15 * di) + ch;  // di*XR + (tap-3di)*XP + ch
      uint4 dv = *(const uint4*)(&xg[pbase + off]);
      h2 v[4];
      v[0] = __builtin_bit_cast(h2, dv.x);
      v[1] = __builtin_bit_cast(h2, dv.y);
      v[2] = __builtin_bit_cast(h2, dv.z);
      v[3] = __builtin_bit_cast(h2, dv.w);
#pragma unroll
      for (int i = 0; i < 4; ++i) {
        const int u = j * 8 + 2 * i;        // compile-time
        const int m = u % 9;
        if (m == 8) {                       // pair crosses gc boundary
          res[u / 9]     += (float)v[i][0] * w8;
          res[u / 9 + 1] += (float)v[i][1] * wb0;
        } else {
#if HAS_FDOT2
          res[u / 9] = __builtin_amdgcn_fdot2(v[i], wp[m], res[u / 9], false);
#else
          res[u / 9] += (float)v[i][0] * ewr[m] + (float)v[i][1] * ewr[m + 1];
#endif
        }
      }
    }
    float* orow = out + (size_t)((((b << 6) + h + hi) << 6) + w0 + pl) * 256 + (g << 4);
    *(float4*)(orow + 0)  = make_float4(res[0],  res[1],  res[2],  res[3]);
    *(float4*)(orow + 4)  = make_float4(res[4],  res[5],  res[6],  res[7]);
    *(float4*)(orow + 8)  = make_float4(res[8],  res[9],  res[10], res[11]);
    *(float4*)(orow + 12) = make_float4(res[12], res[13], res[14], res[15]);
  }
}
} // namespace

extern "C" void kernel_launch(void* const* d_in, const int* in_sizes, int n_in,
                              void* d_out, int out_size, void* d_ws, size_t ws_size,
                              hipStream_t stream) {
  const float* x  = (const float*)d_in[0];
  const float* W1 = (const float*)d_in[1];
  const float* b1 = (const float*)d_in[2];
  const float* W2 = (const float*)d_in[3];
  const float* b2 = (const float*)d_in[4];
  float* out = (float*)d_out;
  _Float16* pack = (_Float16*)d_ws;                        // 73,728 B
  float* b12 = (float*)((char*)d_ws + 73728);              // 576 B
  prep_w12<<<10, 256, 0, stream>>>(W1, b1, W2, b2, pack, b12);
  invo_fused<<<1024, 512, 0, stream>>>(x, pack, b12, out);
}